// Round 4
// baseline (591.884 us; speedup 1.0000x reference)
//
#include <hip/hip_runtime.h>

// Problem constants (B,C,H,W)=(32,64,64,64), code_size=512
#define HWDIM 4096
#define CDIM  64
#define KDIM  512
#define ST_ELEMS   8388608   // 32*64*64*64
#define LOSS_OFF   8519680   // ST_ELEMS + 32*64*64

// R9: fp16-dot2 prune + sound exact rescan.
//  - Pre-kernel packs codebook*256 (pow2 scale -> no fp16 denormals in c)
//    as half2 into d_ws (64KB) + exact sc[512] (np_sumsq64, bit-identical).
//  - Main pass streams 128B/row via s_load_dwordx16 (HALF the scalar bytes
//    of R8) and v_dot2_f32_f16 (HALF the VALU issue). Collects candidate
//    rows per (lane,px,quarter) in a 128-bit mask: f < runmin + MARGIN.
//  - MARGIN=6e-4 soundly covers worst-case fp16 error (A_d <= sqrt(S*sc)
//    *2^-11 ~ 9.4e-5 by Cauchy-Schwarz; e-formula rounding 2R ~ 3.2e-5),
//    so every k that can win under the exact e is collected. Rescan
//    recomputes the EXACT R8 fmaf chain + e-formula per candidate
//    (per-lane fp32 row gathers) -> indices bit-identical to R5-R8.
//  - px=2, K-split x4, 512-thr blocks -> 4096 waves = 4 waves/SIMD
//    (vs R8's 2) at a register peak engineered <= ~110 VGPR.

#define MARGIN 6e-4f

#define REP64(M) M(0) M(1) M(2) M(3) M(4) M(5) M(6) M(7) M(8) M(9) \
  M(10) M(11) M(12) M(13) M(14) M(15) M(16) M(17) M(18) M(19) \
  M(20) M(21) M(22) M(23) M(24) M(25) M(26) M(27) M(28) M(29) \
  M(30) M(31) M(32) M(33) M(34) M(35) M(36) M(37) M(38) M(39) \
  M(40) M(41) M(42) M(43) M(44) M(45) M(46) M(47) M(48) M(49) \
  M(50) M(51) M(52) M(53) M(54) M(55) M(56) M(57) M(58) M(59) \
  M(60) M(61) M(62) M(63)

typedef unsigned int uint;
typedef _Float16 half2_t __attribute__((ext_vector_type(2)));
typedef uint uv16 __attribute__((ext_vector_type(16)));
typedef __attribute__((address_space(4))) const uv16 cuv16;

// numpy fp32 pairwise sum-of-squares of 64 contiguous values — bit-validated.
__device__ __forceinline__ float np_sumsq64(const float a[64]) {
#pragma clang fp contract(off)
  float v[16];
#pragma unroll
  for (int i = 0; i < 16; ++i) {
    float s0 = a[i]      * a[i];
    float s1 = a[i + 16] * a[i + 16];
    float s2 = a[i + 32] * a[i + 32];
    float s3 = a[i + 48] * a[i + 48];
    v[i] = (s0 + s1) + (s2 + s3);
  }
  float t0 = (v[0] + v[8])  + (v[4] + v[12]);
  float t1 = (v[1] + v[9])  + (v[5] + v[13]);
  float t2 = (v[2] + v[10]) + (v[6] + v[14]);
  float t3 = (v[3] + v[11]) + (v[7] + v[15]);
  return (t0 + t2) + (t1 + t3);
}

// Pack two floats as half2-in-u32 (RNE via _Float16 cast; low half = first).
__device__ __forceinline__ uint pkh(float lo, float hi) {
  unsigned short l = __builtin_bit_cast(unsigned short, (_Float16)lo);
  unsigned short h = __builtin_bit_cast(unsigned short, (_Float16)hi);
  return ((uint)h << 16) | (uint)l;
}

#if __has_builtin(__builtin_amdgcn_fdot2)
#define DOT(acc, xu, cu) acc = __builtin_amdgcn_fdot2( \
    __builtin_bit_cast(half2_t, (uint)(xu)), \
    __builtin_bit_cast(half2_t, (uint)(cu)), acc, false);
#else
#define DOT(acc, xu, cu) { half2_t xa_ = __builtin_bit_cast(half2_t, (uint)(xu)); \
    half2_t cb_ = __builtin_bit_cast(half2_t, (uint)(cu)); \
    acc = __builtin_fmaf((float)xa_.y, (float)cb_.y, \
          __builtin_fmaf((float)xa_.x, (float)cb_.x, acc)); }
#endif

// ---------------- pre-kernel: sc[512] + half2 codebook*256 into ws ---------
__global__ void vq_pre(const float* __restrict__ cb, uint* __restrict__ ws) {
  int k = blockIdx.x * 256 + threadIdx.x;
  if (k < KDIM) {
    float row[64];
#pragma unroll
    for (int c = 0; c < 64; ++c) row[c] = cb[(k << 6) + c];
    ((float*)ws)[k] = np_sumsq64(row);
    uint* dst = ws + 512 + k * 32;
#pragma unroll
    for (int j = 0; j < 32; ++j)
      dst[j] = pkh(row[2 * j] * 256.f, row[2 * j + 1] * 256.f);
  }
}

// ---------------- main kernel ----------------------------------------------
__global__ __launch_bounds__(512)
__attribute__((amdgpu_waves_per_eu(4, 4)))
void vq_kernel(
    const float* __restrict__ x, const float* __restrict__ cb,
    const uint* __restrict__ ws,
    float* __restrict__ st, float* __restrict__ idxo, float* __restrict__ loss)
{
  __shared__ float scL[KDIM];
  __shared__ unsigned long long mrg[768];   // 3 quarters x 256 px-slots
  __shared__ float lred[8];

  const int tid = threadIdx.x;
  const int pix = tid & 127;                       // pixel-pair slot
  const int kq  = __builtin_amdgcn_readfirstlane(tid >> 7);  // K-quarter 0..3
  const int b   = blockIdx.x & 31;
  const int p   = ((blockIdx.x >> 5) << 8) + pix;  // px A; px B = p+128

  // sc -> LDS (coalesced; exact values from pre-kernel).
  scL[tid] = ((const float*)ws)[tid];

  // Constant-AS view of the packed fp16 codebook (64B chunks): wave-uniform
  // addresses -> s_load_dwordx16 scalar streaming (row = 2 chunks = 128B).
  cuv16* cw = (cuv16*)(uintptr_t)(ws + 512);

  const float* xpA = x + (size_t)b * (CDIM * HWDIM) + p;
  const float* xpB = xpA + 128;

  // Stage px: compute exact S (bit-identical np tree) + packed fp16 x,
  // loading in tree-groups so the fp32 values never all coexist (VGPR peak).
  float S_A, S_B;
  uint xhA[32], xhB[32];
#define STAGE(XP, SOUT, XH) do { \
    _Pragma("clang fp contract(off)") \
    float vv[16]; \
    _Pragma("unroll") \
    for (int i2 = 0; i2 < 8; ++i2) { \
      const int i = i2 * 2; \
      float a0 = (XP)[(i)      * HWDIM], a1 = (XP)[(i + 1)  * HWDIM]; \
      float b0 = (XP)[(i + 16) * HWDIM], b1 = (XP)[(i + 17) * HWDIM]; \
      float c0 = (XP)[(i + 32) * HWDIM], c1 = (XP)[(i + 33) * HWDIM]; \
      float d0 = (XP)[(i + 48) * HWDIM], d1 = (XP)[(i + 49) * HWDIM]; \
      vv[i]     = (a0 * a0 + b0 * b0) + (c0 * c0 + d0 * d0); \
      vv[i + 1] = (a1 * a1 + b1 * b1) + (c1 * c1 + d1 * d1); \
      (XH)[i2]      = pkh(a0, a1); \
      (XH)[i2 + 8]  = pkh(b0, b1); \
      (XH)[i2 + 16] = pkh(c0, c1); \
      (XH)[i2 + 24] = pkh(d0, d1); \
    } \
    float t0 = (vv[0] + vv[8])  + (vv[4] + vv[12]); \
    float t1 = (vv[1] + vv[9])  + (vv[5] + vv[13]); \
    float t2 = (vv[2] + vv[10]) + (vv[6] + vv[14]); \
    float t3 = (vv[3] + vv[11]) + (vv[7] + vv[15]); \
    SOUT = (t0 + t2) + (t1 + t3); \
  } while (0)
  STAGE(xpA, S_A, xhA);
  STAGE(xpB, S_B, xhB);
#undef STAGE
  __syncthreads();

  // ---- Pass A: fp16 dot2 over this quarter's 128 rows; collect candidate
  // bitmasks (f < runmin + MARGIN). d is scaled by 256 -> f uses -1/128.
  const int qbase = kq << 7;
  float runA = __builtin_inff(), runB = __builtin_inff();
  uint mA0 = 0, mA1 = 0, mA2 = 0, mA3 = 0;
  uint mB0 = 0, mB1 = 0, mB2 = 0, mB3 = 0;

#define PASSJ(J, MA, MB) \
  for (int g = 0; g < 8; ++g) { \
    const int krow = qbase + ((J) << 5) + (g << 2); \
    const int rb = krow << 1; \
    uv16 q0 = cw[rb],     q1 = cw[rb + 1], q2 = cw[rb + 2], q3 = cw[rb + 3]; \
    uv16 q4 = cw[rb + 4], q5 = cw[rb + 5], q6 = cw[rb + 6], q7 = cw[rb + 7]; \
    float d0a = 0.f, d1a = 0.f, d2a = 0.f, d3a = 0.f; \
    float d0b = 0.f, d1b = 0.f, d2b = 0.f, d3b = 0.f; \
    _Pragma("unroll") \
    for (int t = 0; t < 16; ++t) { \
      DOT(d0a, xhA[t], q0[t]) DOT(d0b, xhB[t], q0[t]) \
      DOT(d1a, xhA[t], q2[t]) DOT(d1b, xhB[t], q2[t]) \
      DOT(d2a, xhA[t], q4[t]) DOT(d2b, xhB[t], q4[t]) \
      DOT(d3a, xhA[t], q6[t]) DOT(d3b, xhB[t], q6[t]) \
    } \
    _Pragma("unroll") \
    for (int t = 0; t < 16; ++t) { \
      DOT(d0a, xhA[16 + t], q1[t]) DOT(d0b, xhB[16 + t], q1[t]) \
      DOT(d1a, xhA[16 + t], q3[t]) DOT(d1b, xhB[16 + t], q3[t]) \
      DOT(d2a, xhA[16 + t], q5[t]) DOT(d2b, xhB[16 + t], q5[t]) \
      DOT(d3a, xhA[16 + t], q7[t]) DOT(d3b, xhB[16 + t], q7[t]) \
    } \
    const float s0 = scL[krow], s1 = scL[krow + 1]; \
    const float s2 = scL[krow + 2], s3 = scL[krow + 3]; \
    float f0a = __builtin_fmaf(-0.0078125f, d0a, s0); \
    float f1a = __builtin_fmaf(-0.0078125f, d1a, s1); \
    float f2a = __builtin_fmaf(-0.0078125f, d2a, s2); \
    float f3a = __builtin_fmaf(-0.0078125f, d3a, s3); \
    float f0b = __builtin_fmaf(-0.0078125f, d0b, s0); \
    float f1b = __builtin_fmaf(-0.0078125f, d1b, s1); \
    float f2b = __builtin_fmaf(-0.0078125f, d2b, s2); \
    float f3b = __builtin_fmaf(-0.0078125f, d3b, s3); \
    const float thA = runA + MARGIN, thB = runB + MARGIN; \
    const uint bit0 = 1u << (g << 2); \
    MA |= (f0a < thA ? bit0 : 0u) | (f1a < thA ? (bit0 << 1) : 0u) \
        | (f2a < thA ? (bit0 << 2) : 0u) | (f3a < thA ? (bit0 << 3) : 0u); \
    MB |= (f0b < thB ? bit0 : 0u) | (f1b < thB ? (bit0 << 1) : 0u) \
        | (f2b < thB ? (bit0 << 2) : 0u) | (f3b < thB ? (bit0 << 3) : 0u); \
    runA = fminf(runA, fminf(fminf(f0a, f1a), fminf(f2a, f3a))); \
    runB = fminf(runB, fminf(fminf(f0b, f1b), fminf(f2b, f3b))); \
  }
  PASSJ(0, mA0, mB0)
  PASSJ(1, mA1, mB1)
  PASSJ(2, mA2, mB2)
  PASSJ(3, mA3, mB3)
#undef PASSJ

  // ---- Exact rescan of candidates (bit-identical R8 chain + e-formula).
  float x0,x1,x2,x3,x4,x5,x6,x7,x8,x9,x10,x11,x12,x13,x14,x15,
        x16,x17,x18,x19,x20,x21,x22,x23,x24,x25,x26,x27,x28,x29,x30,x31,
        x32,x33,x34,x35,x36,x37,x38,x39,x40,x41,x42,x43,x44,x45,x46,x47,
        x48,x49,x50,x51,x52,x53,x54,x55,x56,x57,x58,x59,x60,x61,x62,x63;
#define XLD(i) x##i = xq[(i) * HWDIM]; asm("" : "+v"(x##i));

#define FQ(d, R, X0, X1, X2, X3) \
    d = __builtin_fmaf(X0, R.x, d); d = __builtin_fmaf(X1, R.y, d); \
    d = __builtin_fmaf(X2, R.z, d); d = __builtin_fmaf(X3, R.w, d);
#define RESROW(d, rw) \
    { float4 r0 = rw[0], r1 = rw[1], r2 = rw[2], r3 = rw[3]; \
      FQ(d, r0, x0, x1, x2, x3)     FQ(d, r1, x4, x5, x6, x7) \
      FQ(d, r2, x8, x9, x10, x11)   FQ(d, r3, x12, x13, x14, x15) \
      r0 = rw[4]; r1 = rw[5]; r2 = rw[6]; r3 = rw[7]; \
      FQ(d, r0, x16, x17, x18, x19) FQ(d, r1, x20, x21, x22, x23) \
      FQ(d, r2, x24, x25, x26, x27) FQ(d, r3, x28, x29, x30, x31) \
      r0 = rw[8]; r1 = rw[9]; r2 = rw[10]; r3 = rw[11]; \
      FQ(d, r0, x32, x33, x34, x35) FQ(d, r1, x36, x37, x38, x39) \
      FQ(d, r2, x40, x41, x42, x43) FQ(d, r3, x44, x45, x46, x47) \
      r0 = rw[12]; r1 = rw[13]; r2 = rw[14]; r3 = rw[15]; \
      FQ(d, r0, x48, x49, x50, x51) FQ(d, r1, x52, x53, x54, x55) \
      FQ(d, r2, x56, x57, x58, x59) FQ(d, r3, x60, x61, x62, x63) }

#define RES1(MM, J, SS, PK) \
    { uint m_ = MM; \
      while (__any(m_ != 0u)) { \
        if (m_ != 0u) { \
          const int kk = qbase + ((J) << 5) + (__ffs(m_) - 1); \
          const float4* rw = (const float4*)(cb + ((size_t)kk << 6)); \
          float d = 0.f; \
          RESROW(d, rw) \
          float e; \
          { _Pragma("clang fp contract(off)") e = (SS - (d + d)) + scL[kk]; } \
          unsigned long long c_ = \
              ((unsigned long long)__float_as_uint(e) << 32) | (uint)kk; \
          if (c_ < PK) PK = c_; \
          m_ &= m_ - 1u; \
        } \
      } }

  unsigned long long pkA = ~0ull, pkB = ~0ull;
  {  // B first so px A's x-regs stay live into the epilogue.
    const float* xq = xpB;
    REP64(XLD)
    RES1(mB0, 0, S_B, pkB) RES1(mB1, 1, S_B, pkB)
    RES1(mB2, 2, S_B, pkB) RES1(mB3, 3, S_B, pkB)
  }
  {
    const float* xq = xpA;
    REP64(XLD)
    RES1(mA0, 0, S_A, pkA) RES1(mA1, 1, S_A, pkA)
    RES1(mA2, 2, S_A, pkA) RES1(mA3, 3, S_A, pkA)
  }

  // ---- Cross-quarter exact merge (u64 min == first-min semantics).
  if (kq != 0) {
    mrg[((kq - 1) << 8) + pix]       = pkA;
    mrg[((kq - 1) << 8) + pix + 128] = pkB;
  }
  __syncthreads();

  float lsum = 0.f;
  if (kq == 0) {
#pragma unroll
    for (int q = 0; q < 3; ++q) {
      { unsigned long long o = mrg[(q << 8) + pix];       if (o < pkA) pkA = o; }
      { unsigned long long o = mrg[(q << 8) + pix + 128]; if (o < pkB) pkB = o; }
    }
    const int bestiA = (int)(pkA & 0xffffffffull);
    const int bestiB = (int)(pkB & 0xffffffffull);

    // Epilogue A (x-regs hold px A), then reload for B. Identical to R8.
    const float* crowA = cb + (bestiA << 6);
    const float* crowB = cb + (bestiB << 6);
    float* stpA = st + (size_t)b * (CDIM * HWDIM) + p;
    float* stpB = stpA + 128;
    float lsumA = 0.f, lsumB = 0.f;
#define EPIA(i) { float cv = crowA[i]; float df; \
    { _Pragma("clang fp contract(off)") df = cv - x##i; } \
    lsumA = __builtin_fmaf(df, df, lsumA); stpA[(i) * HWDIM] = cv; }
    REP64(EPIA)
#undef EPIA
    {
      const float* xq = xpB;
      REP64(XLD)
    }
#define EPIB(i) { float cv = crowB[i]; float df; \
    { _Pragma("clang fp contract(off)") df = cv - x##i; } \
    lsumB = __builtin_fmaf(df, df, lsumB); stpB[(i) * HWDIM] = cv; }
    REP64(EPIB)
#undef EPIB

    idxo[b * HWDIM + p]       = (float)bestiA;
    idxo[b * HWDIM + p + 128] = (float)bestiB;
    lsum = lsumA + lsumB;
  }
#undef XLD

  // Block reduce loss, one atomic per block. Quarters 1-3 contribute exact
  // zeros -> final value bit-identical to R8's (l0+l1) partial.
#pragma unroll
  for (int off = 32; off > 0; off >>= 1) lsum += __shfl_down(lsum, off);
  if ((tid & 63) == 0) lred[tid >> 6] = lsum;
  __syncthreads();
  if (tid == 0) {
    float t = ((lred[0] + lred[1]) + (lred[2] + lred[3]))
            + ((lred[4] + lred[5]) + (lred[6] + lred[7]));
    atomicAdd(loss, t * (1.25f / 8388608.f));
  }
}

extern "C" void kernel_launch(void* const* d_in, const int* in_sizes, int n_in,
                              void* d_out, int out_size, void* d_ws, size_t ws_size,
                              hipStream_t stream) {
  const float* x  = (const float*)d_in[0];   // (32,64,64,64) fp32
  const float* cb = (const float*)d_in[1];   // (512,64) fp32
  float* st   = (float*)d_out;               // (32,64,64,64)
  float* idxo = (float*)d_out + ST_ELEMS;    // (32,64,64) as float
  float* loss = (float*)d_out + LOSS_OFF;    // scalar
  uint*  ws   = (uint*)d_ws;                 // 2KB sc + 64KB half2 codebook

  hipMemsetAsync(loss, 0, sizeof(float), stream);  // d_out is poisoned each call
  vq_pre<<<dim3(2), dim3(256), 0, stream>>>(cb, ws);
  vq_kernel<<<dim3(512), dim3(512), 0, stream>>>(x, cb, ws, st, idxo, loss);
}

// Round 5
// 582.338 us; speedup vs baseline: 1.0164x; 1.0164x over previous
//
#include <hip/hip_runtime.h>

// Problem constants (B,C,H,W)=(32,64,64,64), code_size=512
#define HWDIM 4096
#define CDIM  64
#define KDIM  512
#define ST_ELEMS   8388608   // 32*64*64*64
#define LOSS_OFF   8519680   // ST_ELEMS + 32*64*64

// R9:  fp16-dot2 prune + sound exact rescan (passed, bit-exact, but spilled:
//      8 live uv16 = 128 u32 > ~102 SGPR budget -> demoted to VGPR -> scratch
//      (FETCH 333MB / WRITE 441MB, VGPR_Count 64, 532us).
// R10: same algorithm, R8's register schedule: per 4-row group, TWO scopes of
//      4 uv16 loads (64 live SGPRs max — identical to R8's proven CHUNK
//      pattern). Scope 1 = channels 0..31 of rows k..k+3 (chunks 2k+{0,2,4,6}),
//      scope 2 = channels 32..63 (chunks 2k+{1,3,5,7}).
//  - MARGIN=6e-4 soundly covers worst-case fp16 error (A_d <= sqrt(S*sc)
//    *2^-11 ~ 9.4e-5 by Cauchy-Schwarz; e-formula rounding 2R ~ 3.2e-5):
//    every k that can win under the exact e is collected; the rescan
//    recomputes the EXACT R8 fmaf chain + e-formula -> indices bit-identical.
//  - px=2, K-split x4, 512-thr blocks -> 4 waves/SIMD.

#define MARGIN 6e-4f

#define REP64(M) M(0) M(1) M(2) M(3) M(4) M(5) M(6) M(7) M(8) M(9) \
  M(10) M(11) M(12) M(13) M(14) M(15) M(16) M(17) M(18) M(19) \
  M(20) M(21) M(22) M(23) M(24) M(25) M(26) M(27) M(28) M(29) \
  M(30) M(31) M(32) M(33) M(34) M(35) M(36) M(37) M(38) M(39) \
  M(40) M(41) M(42) M(43) M(44) M(45) M(46) M(47) M(48) M(49) \
  M(50) M(51) M(52) M(53) M(54) M(55) M(56) M(57) M(58) M(59) \
  M(60) M(61) M(62) M(63)

typedef unsigned int uint;
typedef _Float16 half2_t __attribute__((ext_vector_type(2)));
typedef uint uv16 __attribute__((ext_vector_type(16)));
typedef __attribute__((address_space(4))) const uv16 cuv16;

// numpy fp32 pairwise sum-of-squares of 64 contiguous values — bit-validated.
__device__ __forceinline__ float np_sumsq64(const float a[64]) {
#pragma clang fp contract(off)
  float v[16];
#pragma unroll
  for (int i = 0; i < 16; ++i) {
    float s0 = a[i]      * a[i];
    float s1 = a[i + 16] * a[i + 16];
    float s2 = a[i + 32] * a[i + 32];
    float s3 = a[i + 48] * a[i + 48];
    v[i] = (s0 + s1) + (s2 + s3);
  }
  float t0 = (v[0] + v[8])  + (v[4] + v[12]);
  float t1 = (v[1] + v[9])  + (v[5] + v[13]);
  float t2 = (v[2] + v[10]) + (v[6] + v[14]);
  float t3 = (v[3] + v[11]) + (v[7] + v[15]);
  return (t0 + t2) + (t1 + t3);
}

// Pack two floats as half2-in-u32 (RNE via _Float16 cast; low half = first).
__device__ __forceinline__ uint pkh(float lo, float hi) {
  unsigned short l = __builtin_bit_cast(unsigned short, (_Float16)lo);
  unsigned short h = __builtin_bit_cast(unsigned short, (_Float16)hi);
  return ((uint)h << 16) | (uint)l;
}

#if __has_builtin(__builtin_amdgcn_fdot2)
#define DOT(acc, xu, cu) acc = __builtin_amdgcn_fdot2( \
    __builtin_bit_cast(half2_t, (uint)(xu)), \
    __builtin_bit_cast(half2_t, (uint)(cu)), acc, false);
#else
#define DOT(acc, xu, cu) { half2_t xa_ = __builtin_bit_cast(half2_t, (uint)(xu)); \
    half2_t cb_ = __builtin_bit_cast(half2_t, (uint)(cu)); \
    acc = __builtin_fmaf((float)xa_.y, (float)cb_.y, \
          __builtin_fmaf((float)xa_.x, (float)cb_.x, acc)); }
#endif

// ---------------- pre-kernel: sc[512] + half2 codebook*256 into ws ---------
__global__ void vq_pre(const float* __restrict__ cb, uint* __restrict__ ws) {
  int k = blockIdx.x * 256 + threadIdx.x;
  if (k < KDIM) {
    float row[64];
#pragma unroll
    for (int c = 0; c < 64; ++c) row[c] = cb[(k << 6) + c];
    ((float*)ws)[k] = np_sumsq64(row);
    uint* dst = ws + 512 + k * 32;
#pragma unroll
    for (int j = 0; j < 32; ++j)
      dst[j] = pkh(row[2 * j] * 256.f, row[2 * j + 1] * 256.f);
  }
}

// ---------------- main kernel ----------------------------------------------
__global__ __launch_bounds__(512)
__attribute__((amdgpu_waves_per_eu(4, 4)))
void vq_kernel(
    const float* __restrict__ x, const float* __restrict__ cb,
    const uint* __restrict__ ws,
    float* __restrict__ st, float* __restrict__ idxo, float* __restrict__ loss)
{
  __shared__ float scL[KDIM];
  __shared__ unsigned long long mrg[768];   // 3 quarters x 256 px-slots
  __shared__ float lred[8];

  const int tid = threadIdx.x;
  const int pix = tid & 127;                       // pixel-pair slot
  const int kq  = __builtin_amdgcn_readfirstlane(tid >> 7);  // K-quarter 0..3
  const int b   = blockIdx.x & 31;
  const int p   = ((blockIdx.x >> 5) << 8) + pix;  // px A; px B = p+128

  // sc -> LDS (coalesced; exact values from pre-kernel).
  scL[tid] = ((const float*)ws)[tid];

  // Constant-AS view of the packed fp16 codebook (64B chunks): wave-uniform
  // addresses -> s_load_dwordx16 scalar streaming (row = 2 chunks = 128B).
  cuv16* cw = (cuv16*)(uintptr_t)(ws + 512);

  const float* xpA = x + (size_t)b * (CDIM * HWDIM) + p;
  const float* xpB = xpA + 128;

  // Stage px: compute exact S (bit-identical np tree) + packed fp16 x,
  // loading in tree-groups so the fp32 values never all coexist (VGPR peak).
  float S_A, S_B;
  uint xhA[32], xhB[32];
#define STAGE(XP, SOUT, XH) do { \
    _Pragma("clang fp contract(off)") \
    float vv[16]; \
    _Pragma("unroll") \
    for (int i2 = 0; i2 < 8; ++i2) { \
      const int i = i2 * 2; \
      float a0 = (XP)[(i)      * HWDIM], a1 = (XP)[(i + 1)  * HWDIM]; \
      float b0 = (XP)[(i + 16) * HWDIM], b1 = (XP)[(i + 17) * HWDIM]; \
      float c0 = (XP)[(i + 32) * HWDIM], c1 = (XP)[(i + 33) * HWDIM]; \
      float d0 = (XP)[(i + 48) * HWDIM], d1 = (XP)[(i + 49) * HWDIM]; \
      vv[i]     = (a0 * a0 + b0 * b0) + (c0 * c0 + d0 * d0); \
      vv[i + 1] = (a1 * a1 + b1 * b1) + (c1 * c1 + d1 * d1); \
      (XH)[i2]      = pkh(a0, a1); \
      (XH)[i2 + 8]  = pkh(b0, b1); \
      (XH)[i2 + 16] = pkh(c0, c1); \
      (XH)[i2 + 24] = pkh(d0, d1); \
    } \
    float t0 = (vv[0] + vv[8])  + (vv[4] + vv[12]); \
    float t1 = (vv[1] + vv[9])  + (vv[5] + vv[13]); \
    float t2 = (vv[2] + vv[10]) + (vv[6] + vv[14]); \
    float t3 = (vv[3] + vv[11]) + (vv[7] + vv[15]); \
    SOUT = (t0 + t2) + (t1 + t3); \
  } while (0)
  STAGE(xpA, S_A, xhA);
  STAGE(xpB, S_B, xhB);
#undef STAGE
  __syncthreads();

  // ---- Pass A: fp16 dot2 over this quarter's 128 rows; collect candidate
  // bitmasks (f < runmin + MARGIN). d is scaled by 256^2 -> f uses -2/256^2
  // = -0.0078125/4... note: c scaled by 256, x NOT scaled -> d = 256*<x,c>,
  // f = sc - 2*d/256 -> coefficient -2/256 = -0.0078125. (Same as R9.)
  const int qbase = kq << 7;
  float runA = __builtin_inff(), runB = __builtin_inff();
  uint mA0 = 0, mA1 = 0, mA2 = 0, mA3 = 0;
  uint mB0 = 0, mB1 = 0, mB2 = 0, mB3 = 0;

  // Register schedule mirrors R8: two scopes of 4 live uv16 (64 SGPRs peak).
#define PASSJ(J, MA, MB) \
  for (int g = 0; g < 8; ++g) { \
    const int krow = qbase + ((J) << 5) + (g << 2); \
    const int rb = krow << 1;     /* uv16 chunk index: row k = chunks 2k,2k+1 */ \
    float d0a = 0.f, d1a = 0.f, d2a = 0.f, d3a = 0.f; \
    float d0b = 0.f, d1b = 0.f, d2b = 0.f, d3b = 0.f; \
    {  /* channels 0..31 of rows krow..krow+3 */ \
      uv16 q0 = cw[rb], q1 = cw[rb + 2], q2 = cw[rb + 4], q3 = cw[rb + 6]; \
      _Pragma("unroll") \
      for (int t = 0; t < 16; ++t) { \
        DOT(d0a, xhA[t], q0[t]) DOT(d0b, xhB[t], q0[t]) \
        DOT(d1a, xhA[t], q1[t]) DOT(d1b, xhB[t], q1[t]) \
        DOT(d2a, xhA[t], q2[t]) DOT(d2b, xhB[t], q2[t]) \
        DOT(d3a, xhA[t], q3[t]) DOT(d3b, xhB[t], q3[t]) \
      } \
    } \
    {  /* channels 32..63 of rows krow..krow+3 */ \
      uv16 q0 = cw[rb + 1], q1 = cw[rb + 3], q2 = cw[rb + 5], q3 = cw[rb + 7]; \
      _Pragma("unroll") \
      for (int t = 0; t < 16; ++t) { \
        DOT(d0a, xhA[16 + t], q0[t]) DOT(d0b, xhB[16 + t], q0[t]) \
        DOT(d1a, xhA[16 + t], q1[t]) DOT(d1b, xhB[16 + t], q1[t]) \
        DOT(d2a, xhA[16 + t], q2[t]) DOT(d2b, xhB[16 + t], q2[t]) \
        DOT(d3a, xhA[16 + t], q3[t]) DOT(d3b, xhB[16 + t], q3[t]) \
      } \
    } \
    const float s0 = scL[krow], s1 = scL[krow + 1]; \
    const float s2 = scL[krow + 2], s3 = scL[krow + 3]; \
    float f0a = __builtin_fmaf(-0.0078125f, d0a, s0); \
    float f1a = __builtin_fmaf(-0.0078125f, d1a, s1); \
    float f2a = __builtin_fmaf(-0.0078125f, d2a, s2); \
    float f3a = __builtin_fmaf(-0.0078125f, d3a, s3); \
    float f0b = __builtin_fmaf(-0.0078125f, d0b, s0); \
    float f1b = __builtin_fmaf(-0.0078125f, d1b, s1); \
    float f2b = __builtin_fmaf(-0.0078125f, d2b, s2); \
    float f3b = __builtin_fmaf(-0.0078125f, d3b, s3); \
    const float thA = runA + MARGIN, thB = runB + MARGIN; \
    const uint bit0 = 1u << (g << 2); \
    MA |= (f0a < thA ? bit0 : 0u) | (f1a < thA ? (bit0 << 1) : 0u) \
        | (f2a < thA ? (bit0 << 2) : 0u) | (f3a < thA ? (bit0 << 3) : 0u); \
    MB |= (f0b < thB ? bit0 : 0u) | (f1b < thB ? (bit0 << 1) : 0u) \
        | (f2b < thB ? (bit0 << 2) : 0u) | (f3b < thB ? (bit0 << 3) : 0u); \
    runA = fminf(runA, fminf(fminf(f0a, f1a), fminf(f2a, f3a))); \
    runB = fminf(runB, fminf(fminf(f0b, f1b), fminf(f2b, f3b))); \
  }
  PASSJ(0, mA0, mB0)
  PASSJ(1, mA1, mB1)
  PASSJ(2, mA2, mB2)
  PASSJ(3, mA3, mB3)
#undef PASSJ

  // ---- Exact rescan of candidates (bit-identical R8 chain + e-formula).
  float x0,x1,x2,x3,x4,x5,x6,x7,x8,x9,x10,x11,x12,x13,x14,x15,
        x16,x17,x18,x19,x20,x21,x22,x23,x24,x25,x26,x27,x28,x29,x30,x31,
        x32,x33,x34,x35,x36,x37,x38,x39,x40,x41,x42,x43,x44,x45,x46,x47,
        x48,x49,x50,x51,x52,x53,x54,x55,x56,x57,x58,x59,x60,x61,x62,x63;
#define XLD(i) x##i = xq[(i) * HWDIM]; asm("" : "+v"(x##i));

#define FQ(d, R, X0, X1, X2, X3) \
    d = __builtin_fmaf(X0, R.x, d); d = __builtin_fmaf(X1, R.y, d); \
    d = __builtin_fmaf(X2, R.z, d); d = __builtin_fmaf(X3, R.w, d);
#define RESROW(d, rw) \
    { float4 r0 = rw[0], r1 = rw[1], r2 = rw[2], r3 = rw[3]; \
      FQ(d, r0, x0, x1, x2, x3)     FQ(d, r1, x4, x5, x6, x7) \
      FQ(d, r2, x8, x9, x10, x11)   FQ(d, r3, x12, x13, x14, x15) \
      r0 = rw[4]; r1 = rw[5]; r2 = rw[6]; r3 = rw[7]; \
      FQ(d, r0, x16, x17, x18, x19) FQ(d, r1, x20, x21, x22, x23) \
      FQ(d, r2, x24, x25, x26, x27) FQ(d, r3, x28, x29, x30, x31) \
      r0 = rw[8]; r1 = rw[9]; r2 = rw[10]; r3 = rw[11]; \
      FQ(d, r0, x32, x33, x34, x35) FQ(d, r1, x36, x37, x38, x39) \
      FQ(d, r2, x40, x41, x42, x43) FQ(d, r3, x44, x45, x46, x47) \
      r0 = rw[12]; r1 = rw[13]; r2 = rw[14]; r3 = rw[15]; \
      FQ(d, r0, x48, x49, x50, x51) FQ(d, r1, x52, x53, x54, x55) \
      FQ(d, r2, x56, x57, x58, x59) FQ(d, r3, x60, x61, x62, x63) }

#define RES1(MM, J, SS, PK) \
    { uint m_ = MM; \
      while (__any(m_ != 0u)) { \
        if (m_ != 0u) { \
          const int kk = qbase + ((J) << 5) + (__ffs(m_) - 1); \
          const float4* rw = (const float4*)(cb + ((size_t)kk << 6)); \
          float d = 0.f; \
          RESROW(d, rw) \
          float e; \
          { _Pragma("clang fp contract(off)") e = (SS - (d + d)) + scL[kk]; } \
          unsigned long long c_ = \
              ((unsigned long long)__float_as_uint(e) << 32) | (uint)kk; \
          if (c_ < PK) PK = c_; \
          m_ &= m_ - 1u; \
        } \
      } }

  unsigned long long pkA = ~0ull, pkB = ~0ull;
  {  // B first so px A's x-regs stay live into the epilogue.
    const float* xq = xpB;
    REP64(XLD)
    RES1(mB0, 0, S_B, pkB) RES1(mB1, 1, S_B, pkB)
    RES1(mB2, 2, S_B, pkB) RES1(mB3, 3, S_B, pkB)
  }
  {
    const float* xq = xpA;
    REP64(XLD)
    RES1(mA0, 0, S_A, pkA) RES1(mA1, 1, S_A, pkA)
    RES1(mA2, 2, S_A, pkA) RES1(mA3, 3, S_A, pkA)
  }

  // ---- Cross-quarter exact merge (u64 min == first-min semantics).
  if (kq != 0) {
    mrg[((kq - 1) << 8) + pix]       = pkA;
    mrg[((kq - 1) << 8) + pix + 128] = pkB;
  }
  __syncthreads();

  float lsum = 0.f;
  if (kq == 0) {
#pragma unroll
    for (int q = 0; q < 3; ++q) {
      { unsigned long long o = mrg[(q << 8) + pix];       if (o < pkA) pkA = o; }
      { unsigned long long o = mrg[(q << 8) + pix + 128]; if (o < pkB) pkB = o; }
    }
    const int bestiA = (int)(pkA & 0xffffffffull);
    const int bestiB = (int)(pkB & 0xffffffffull);

    // Epilogue A (x-regs hold px A), then reload for B. Identical to R8.
    const float* crowA = cb + (bestiA << 6);
    const float* crowB = cb + (bestiB << 6);
    float* stpA = st + (size_t)b * (CDIM * HWDIM) + p;
    float* stpB = stpA + 128;
    float lsumA = 0.f, lsumB = 0.f;
#define EPIA(i) { float cv = crowA[i]; float df; \
    { _Pragma("clang fp contract(off)") df = cv - x##i; } \
    lsumA = __builtin_fmaf(df, df, lsumA); stpA[(i) * HWDIM] = cv; }
    REP64(EPIA)
#undef EPIA
    {
      const float* xq = xpB;
      REP64(XLD)
    }
#define EPIB(i) { float cv = crowB[i]; float df; \
    { _Pragma("clang fp contract(off)") df = cv - x##i; } \
    lsumB = __builtin_fmaf(df, df, lsumB); stpB[(i) * HWDIM] = cv; }
    REP64(EPIB)
#undef EPIB

    idxo[b * HWDIM + p]       = (float)bestiA;
    idxo[b * HWDIM + p + 128] = (float)bestiB;
    lsum = lsumA + lsumB;
  }
#undef XLD

  // Block reduce loss, one atomic per block. Quarters 1-3 contribute exact
  // zeros -> final value bit-identical to R8's (l0+l1) partial.
#pragma unroll
  for (int off = 32; off > 0; off >>= 1) lsum += __shfl_down(lsum, off);
  if ((tid & 63) == 0) lred[tid >> 6] = lsum;
  __syncthreads();
  if (tid == 0) {
    float t = ((lred[0] + lred[1]) + (lred[2] + lred[3]))
            + ((lred[4] + lred[5]) + (lred[6] + lred[7]));
    atomicAdd(loss, t * (1.25f / 8388608.f));
  }
}

extern "C" void kernel_launch(void* const* d_in, const int* in_sizes, int n_in,
                              void* d_out, int out_size, void* d_ws, size_t ws_size,
                              hipStream_t stream) {
  const float* x  = (const float*)d_in[0];   // (32,64,64,64) fp32
  const float* cb = (const float*)d_in[1];   // (512,64) fp32
  float* st   = (float*)d_out;               // (32,64,64,64)
  float* idxo = (float*)d_out + ST_ELEMS;    // (32,64,64) as float
  float* loss = (float*)d_out + LOSS_OFF;    // scalar
  uint*  ws   = (uint*)d_ws;                 // 2KB sc + 64KB half2 codebook

  hipMemsetAsync(loss, 0, sizeof(float), stream);  // d_out is poisoned each call
  vq_pre<<<dim3(2), dim3(256), 0, stream>>>(cb, ws);
  vq_kernel<<<dim3(512), dim3(512), 0, stream>>>(x, cb, ws, st, idxo, loss);
}

// Round 6
// 300.291 us; speedup vs baseline: 1.9710x; 1.9392x over previous
//
#include <hip/hip_runtime.h>

// Problem constants (B,C,H,W)=(32,64,64,64), code_size=512
#define HWDIM 4096
#define CDIM  64
#define KDIM  512
#define ST_ELEMS   8388608   // 32*64*64*64
#define LOSS_OFF   8519680   // ST_ELEMS + 32*64*64

// R9/R10: fp16-dot2 prune + sound exact rescan — algorithm VALIDATED (passed,
//   absmax bit-identical) but spilled to scratch: 512-thr + waves_per_eu(4,4)
//   caps the unified reg budget at 128/wave; allocator split 64 arch + 64 acc
//   -> ~400 dwords/thread scratch (FETCH 324MB, WRITE 432MB), 516us.
// R11: SAME algorithm in R8's proven register regime: 256-thr blocks,
//   waves_per_eu(2,2) (cap 256 — R8 measured VGPR=128, FETCH 17MB, no spill),
//   px=2, K-split x2 (khalf). Per thread: 2 px, 256 codes, masks 8 u32/px.
//  - Main pass streams rows as 2x s_load_dwordx16 (128B fp16/row, HALF of
//    R8's scalar bytes) + v_dot2_f32_f16 (HALF the VALU issue).
//  - MARGIN=6e-4 soundly covers worst-case fp16 error (A_d <= sqrt(S*sc)
//    *2^-11 ~ 9.4e-5 by Cauchy-Schwarz; e-formula rounding 2R ~ 3.2e-5):
//    every k that can win under the exact e is collected; the rescan
//    recomputes the EXACT R8 fmaf chain + e-formula -> indices bit-identical.

#define MARGIN 6e-4f

#define REP64(M) M(0) M(1) M(2) M(3) M(4) M(5) M(6) M(7) M(8) M(9) \
  M(10) M(11) M(12) M(13) M(14) M(15) M(16) M(17) M(18) M(19) \
  M(20) M(21) M(22) M(23) M(24) M(25) M(26) M(27) M(28) M(29) \
  M(30) M(31) M(32) M(33) M(34) M(35) M(36) M(37) M(38) M(39) \
  M(40) M(41) M(42) M(43) M(44) M(45) M(46) M(47) M(48) M(49) \
  M(50) M(51) M(52) M(53) M(54) M(55) M(56) M(57) M(58) M(59) \
  M(60) M(61) M(62) M(63)

typedef unsigned int uint;
typedef _Float16 half2_t __attribute__((ext_vector_type(2)));
typedef uint uv16 __attribute__((ext_vector_type(16)));
typedef __attribute__((address_space(4))) const uv16 cuv16;

// numpy fp32 pairwise sum-of-squares of 64 contiguous values — bit-validated.
__device__ __forceinline__ float np_sumsq64(const float a[64]) {
#pragma clang fp contract(off)
  float v[16];
#pragma unroll
  for (int i = 0; i < 16; ++i) {
    float s0 = a[i]      * a[i];
    float s1 = a[i + 16] * a[i + 16];
    float s2 = a[i + 32] * a[i + 32];
    float s3 = a[i + 48] * a[i + 48];
    v[i] = (s0 + s1) + (s2 + s3);
  }
  float t0 = (v[0] + v[8])  + (v[4] + v[12]);
  float t1 = (v[1] + v[9])  + (v[5] + v[13]);
  float t2 = (v[2] + v[10]) + (v[6] + v[14]);
  float t3 = (v[3] + v[11]) + (v[7] + v[15]);
  return (t0 + t2) + (t1 + t3);
}

// Pack two floats as half2-in-u32 (RNE via _Float16 cast; low half = first).
__device__ __forceinline__ uint pkh(float lo, float hi) {
  unsigned short l = __builtin_bit_cast(unsigned short, (_Float16)lo);
  unsigned short h = __builtin_bit_cast(unsigned short, (_Float16)hi);
  return ((uint)h << 16) | (uint)l;
}

#if __has_builtin(__builtin_amdgcn_fdot2)
#define DOT(acc, xu, cu) acc = __builtin_amdgcn_fdot2( \
    __builtin_bit_cast(half2_t, (uint)(xu)), \
    __builtin_bit_cast(half2_t, (uint)(cu)), acc, false);
#else
#define DOT(acc, xu, cu) { half2_t xa_ = __builtin_bit_cast(half2_t, (uint)(xu)); \
    half2_t cb_ = __builtin_bit_cast(half2_t, (uint)(cu)); \
    acc = __builtin_fmaf((float)xa_.y, (float)cb_.y, \
          __builtin_fmaf((float)xa_.x, (float)cb_.x, acc)); }
#endif

// ---------------- pre-kernel: sc[512] + half2 codebook*256 into ws ---------
__global__ void vq_pre(const float* __restrict__ cb, uint* __restrict__ ws) {
  int k = blockIdx.x * 256 + threadIdx.x;
  if (k < KDIM) {
    float row[64];
#pragma unroll
    for (int c = 0; c < 64; ++c) row[c] = cb[(k << 6) + c];
    ((float*)ws)[k] = np_sumsq64(row);
    uint* dst = ws + 512 + k * 32;
#pragma unroll
    for (int j = 0; j < 32; ++j)
      dst[j] = pkh(row[2 * j] * 256.f, row[2 * j + 1] * 256.f);
  }
}

// ---------------- main kernel ----------------------------------------------
__global__ __launch_bounds__(256)
__attribute__((amdgpu_waves_per_eu(2, 2)))
void vq_kernel(
    const float* __restrict__ x, const float* __restrict__ cb,
    const uint* __restrict__ ws,
    float* __restrict__ st, float* __restrict__ idxo, float* __restrict__ loss)
{
  __shared__ float scL[KDIM];
  __shared__ unsigned long long mrg[256];
  __shared__ float lred[4];

  const int tid = threadIdx.x;
  const int pix = tid & 127;                       // pixel-pair slot
  // tid>>7 IS wave-uniform (64-thread waves don't straddle 128) — force SGPR.
  const int khalf = __builtin_amdgcn_readfirstlane(tid >> 7);
  const int b   = blockIdx.x & 31;
  const int p   = ((blockIdx.x >> 5) << 8) + pix;  // px A; px B = p+128

  // sc -> LDS (exact values from pre-kernel; bit-identical np_sumsq64).
  scL[tid]       = ((const float*)ws)[tid];
  scL[tid + 256] = ((const float*)ws)[tid + 256];

  // Constant-AS view of the packed fp16 codebook (64B chunks): wave-uniform
  // addresses -> s_load_dwordx16 scalar streaming (row = 2 chunks = 128B).
  cuv16* cw = (cuv16*)(uintptr_t)(ws + 512);

  const float* xpA = x + (size_t)b * (CDIM * HWDIM) + p;
  const float* xpB = xpA + 128;

  // Stage px: compute exact S (bit-identical np tree) + packed fp16 x,
  // loading in tree-groups so the fp32 values never all coexist.
  float S_A, S_B;
  uint xhA[32], xhB[32];
#define STAGE(XP, SOUT, XH) do { \
    _Pragma("clang fp contract(off)") \
    float vv[16]; \
    _Pragma("unroll") \
    for (int i2 = 0; i2 < 8; ++i2) { \
      const int i = i2 * 2; \
      float a0 = (XP)[(i)      * HWDIM], a1 = (XP)[(i + 1)  * HWDIM]; \
      float b0 = (XP)[(i + 16) * HWDIM], b1 = (XP)[(i + 17) * HWDIM]; \
      float c0 = (XP)[(i + 32) * HWDIM], c1 = (XP)[(i + 33) * HWDIM]; \
      float d0 = (XP)[(i + 48) * HWDIM], d1 = (XP)[(i + 49) * HWDIM]; \
      vv[i]     = (a0 * a0 + b0 * b0) + (c0 * c0 + d0 * d0); \
      vv[i + 1] = (a1 * a1 + b1 * b1) + (c1 * c1 + d1 * d1); \
      (XH)[i2]      = pkh(a0, a1); \
      (XH)[i2 + 8]  = pkh(b0, b1); \
      (XH)[i2 + 16] = pkh(c0, c1); \
      (XH)[i2 + 24] = pkh(d0, d1); \
    } \
    float t0 = (vv[0] + vv[8])  + (vv[4] + vv[12]); \
    float t1 = (vv[1] + vv[9])  + (vv[5] + vv[13]); \
    float t2 = (vv[2] + vv[10]) + (vv[6] + vv[14]); \
    float t3 = (vv[3] + vv[11]) + (vv[7] + vv[15]); \
    SOUT = (t0 + t2) + (t1 + t3); \
  } while (0)
  STAGE(xpA, S_A, xhA);
  STAGE(xpB, S_B, xhB);
#undef STAGE
  __syncthreads();

  // ---- Pass: fp16 dot2 over this half's 256 rows; collect candidate
  // bitmasks (f < runmin + MARGIN). c scaled by 256 -> f = sc - 2*d/256
  // -> coefficient -2/256 = -0.0078125.
  const int qbase = khalf << 8;
  float runA = __builtin_inff(), runB = __builtin_inff();
  uint mA0 = 0, mA1 = 0, mA2 = 0, mA3 = 0, mA4 = 0, mA5 = 0, mA6 = 0, mA7 = 0;
  uint mB0 = 0, mB1 = 0, mB2 = 0, mB3 = 0, mB4 = 0, mB5 = 0, mB6 = 0, mB7 = 0;

  // Register schedule mirrors R8: two scopes of 4 live uv16 (64 SGPRs peak).
#define PASSJ(J, MA, MB) \
  for (int g = 0; g < 8; ++g) { \
    const int krow = qbase + ((J) << 5) + (g << 2); \
    const int rb = krow << 1;     /* uv16 chunk index: row k = chunks 2k,2k+1 */ \
    float d0a = 0.f, d1a = 0.f, d2a = 0.f, d3a = 0.f; \
    float d0b = 0.f, d1b = 0.f, d2b = 0.f, d3b = 0.f; \
    {  /* channels 0..31 of rows krow..krow+3 */ \
      uv16 q0 = cw[rb], q1 = cw[rb + 2], q2 = cw[rb + 4], q3 = cw[rb + 6]; \
      _Pragma("unroll") \
      for (int t = 0; t < 16; ++t) { \
        DOT(d0a, xhA[t], q0[t]) DOT(d0b, xhB[t], q0[t]) \
        DOT(d1a, xhA[t], q1[t]) DOT(d1b, xhB[t], q1[t]) \
        DOT(d2a, xhA[t], q2[t]) DOT(d2b, xhB[t], q2[t]) \
        DOT(d3a, xhA[t], q3[t]) DOT(d3b, xhB[t], q3[t]) \
      } \
    } \
    {  /* channels 32..63 of rows krow..krow+3 */ \
      uv16 q0 = cw[rb + 1], q1 = cw[rb + 3], q2 = cw[rb + 5], q3 = cw[rb + 7]; \
      _Pragma("unroll") \
      for (int t = 0; t < 16; ++t) { \
        DOT(d0a, xhA[16 + t], q0[t]) DOT(d0b, xhB[16 + t], q0[t]) \
        DOT(d1a, xhA[16 + t], q1[t]) DOT(d1b, xhB[16 + t], q1[t]) \
        DOT(d2a, xhA[16 + t], q2[t]) DOT(d2b, xhB[16 + t], q2[t]) \
        DOT(d3a, xhA[16 + t], q3[t]) DOT(d3b, xhB[16 + t], q3[t]) \
      } \
    } \
    const float s0 = scL[krow], s1 = scL[krow + 1]; \
    const float s2 = scL[krow + 2], s3 = scL[krow + 3]; \
    float f0a = __builtin_fmaf(-0.0078125f, d0a, s0); \
    float f1a = __builtin_fmaf(-0.0078125f, d1a, s1); \
    float f2a = __builtin_fmaf(-0.0078125f, d2a, s2); \
    float f3a = __builtin_fmaf(-0.0078125f, d3a, s3); \
    float f0b = __builtin_fmaf(-0.0078125f, d0b, s0); \
    float f1b = __builtin_fmaf(-0.0078125f, d1b, s1); \
    float f2b = __builtin_fmaf(-0.0078125f, d2b, s2); \
    float f3b = __builtin_fmaf(-0.0078125f, d3b, s3); \
    const float thA = runA + MARGIN, thB = runB + MARGIN; \
    const uint bit0 = 1u << (g << 2); \
    MA |= (f0a < thA ? bit0 : 0u) | (f1a < thA ? (bit0 << 1) : 0u) \
        | (f2a < thA ? (bit0 << 2) : 0u) | (f3a < thA ? (bit0 << 3) : 0u); \
    MB |= (f0b < thB ? bit0 : 0u) | (f1b < thB ? (bit0 << 1) : 0u) \
        | (f2b < thB ? (bit0 << 2) : 0u) | (f3b < thB ? (bit0 << 3) : 0u); \
    runA = fminf(runA, fminf(fminf(f0a, f1a), fminf(f2a, f3a))); \
    runB = fminf(runB, fminf(fminf(f0b, f1b), fminf(f2b, f3b))); \
  }
  PASSJ(0, mA0, mB0)
  PASSJ(1, mA1, mB1)
  PASSJ(2, mA2, mB2)
  PASSJ(3, mA3, mB3)
  PASSJ(4, mA4, mB4)
  PASSJ(5, mA5, mB5)
  PASSJ(6, mA6, mB6)
  PASSJ(7, mA7, mB7)
#undef PASSJ

  // ---- Exact rescan of candidates (bit-identical R8 chain + e-formula).
  float x0,x1,x2,x3,x4,x5,x6,x7,x8,x9,x10,x11,x12,x13,x14,x15,
        x16,x17,x18,x19,x20,x21,x22,x23,x24,x25,x26,x27,x28,x29,x30,x31,
        x32,x33,x34,x35,x36,x37,x38,x39,x40,x41,x42,x43,x44,x45,x46,x47,
        x48,x49,x50,x51,x52,x53,x54,x55,x56,x57,x58,x59,x60,x61,x62,x63;
#define XLD(i) x##i = xq[(i) * HWDIM]; asm("" : "+v"(x##i));

#define FQ(d, R, X0, X1, X2, X3) \
    d = __builtin_fmaf(X0, R.x, d); d = __builtin_fmaf(X1, R.y, d); \
    d = __builtin_fmaf(X2, R.z, d); d = __builtin_fmaf(X3, R.w, d);
#define RESROW(d, rw) \
    { float4 r0 = rw[0], r1 = rw[1], r2 = rw[2], r3 = rw[3]; \
      FQ(d, r0, x0, x1, x2, x3)     FQ(d, r1, x4, x5, x6, x7) \
      FQ(d, r2, x8, x9, x10, x11)   FQ(d, r3, x12, x13, x14, x15) \
      r0 = rw[4]; r1 = rw[5]; r2 = rw[6]; r3 = rw[7]; \
      FQ(d, r0, x16, x17, x18, x19) FQ(d, r1, x20, x21, x22, x23) \
      FQ(d, r2, x24, x25, x26, x27) FQ(d, r3, x28, x29, x30, x31) \
      r0 = rw[8]; r1 = rw[9]; r2 = rw[10]; r3 = rw[11]; \
      FQ(d, r0, x32, x33, x34, x35) FQ(d, r1, x36, x37, x38, x39) \
      FQ(d, r2, x40, x41, x42, x43) FQ(d, r3, x44, x45, x46, x47) \
      r0 = rw[12]; r1 = rw[13]; r2 = rw[14]; r3 = rw[15]; \
      FQ(d, r0, x48, x49, x50, x51) FQ(d, r1, x52, x53, x54, x55) \
      FQ(d, r2, x56, x57, x58, x59) FQ(d, r3, x60, x61, x62, x63) }

#define RES1(MM, J, SS, PK) \
    { uint m_ = MM; \
      while (__any(m_ != 0u)) { \
        if (m_ != 0u) { \
          const int kk = qbase + ((J) << 5) + (__ffs(m_) - 1); \
          const float4* rw = (const float4*)(cb + ((size_t)kk << 6)); \
          float d = 0.f; \
          RESROW(d, rw) \
          float e; \
          { _Pragma("clang fp contract(off)") e = (SS - (d + d)) + scL[kk]; } \
          unsigned long long c_ = \
              ((unsigned long long)__float_as_uint(e) << 32) | (uint)kk; \
          if (c_ < PK) PK = c_; \
          m_ &= m_ - 1u; \
        } \
      } }

  unsigned long long pkA = ~0ull, pkB = ~0ull;
  {  // B first so px A's x-regs stay live into the epilogue.
    const float* xq = xpB;
    REP64(XLD)
    RES1(mB0, 0, S_B, pkB) RES1(mB1, 1, S_B, pkB)
    RES1(mB2, 2, S_B, pkB) RES1(mB3, 3, S_B, pkB)
    RES1(mB4, 4, S_B, pkB) RES1(mB5, 5, S_B, pkB)
    RES1(mB6, 6, S_B, pkB) RES1(mB7, 7, S_B, pkB)
  }
  {
    const float* xq = xpA;
    REP64(XLD)
    RES1(mA0, 0, S_A, pkA) RES1(mA1, 1, S_A, pkA)
    RES1(mA2, 2, S_A, pkA) RES1(mA3, 3, S_A, pkA)
    RES1(mA4, 4, S_A, pkA) RES1(mA5, 5, S_A, pkA)
    RES1(mA6, 6, S_A, pkA) RES1(mA7, 7, S_A, pkA)
  }

  // ---- Cross-half exact merge (u64 min == first-min semantics: distances
  // are positive so fp32 bits order identically; idx in low word).
  if (khalf) { mrg[pix] = pkA; mrg[pix + 128] = pkB; }
  __syncthreads();

  float lsum = 0.f;
  if (!khalf) {
    { unsigned long long o = mrg[pix];       if (o < pkA) pkA = o; }
    { unsigned long long o = mrg[pix + 128]; if (o < pkB) pkB = o; }
    const int bestiA = (int)(pkA & 0xffffffffull);
    const int bestiB = (int)(pkB & 0xffffffffull);

    // Epilogue A (x-regs hold px A), then reload for B. Identical to R8.
    const float* crowA = cb + (bestiA << 6);
    const float* crowB = cb + (bestiB << 6);
    float* stpA = st + (size_t)b * (CDIM * HWDIM) + p;
    float* stpB = stpA + 128;
    float lsumA = 0.f, lsumB = 0.f;
#define EPIA(i) { float cv = crowA[i]; float df; \
    { _Pragma("clang fp contract(off)") df = cv - x##i; } \
    lsumA = __builtin_fmaf(df, df, lsumA); stpA[(i) * HWDIM] = cv; }
    REP64(EPIA)
#undef EPIA
    {
      const float* xq = xpB;
      REP64(XLD)
    }
#define EPIB(i) { float cv = crowB[i]; float df; \
    { _Pragma("clang fp contract(off)") df = cv - x##i; } \
    lsumB = __builtin_fmaf(df, df, lsumB); stpB[(i) * HWDIM] = cv; }
    REP64(EPIB)
#undef EPIB

    idxo[b * HWDIM + p]       = (float)bestiA;
    idxo[b * HWDIM + p + 128] = (float)bestiB;
    lsum = lsumA + lsumB;
  }
#undef XLD

  // Block reduce loss, one atomic per block (R8's exact tree; waves 2-3
  // contribute exact zeros, t + 0.0f == t bitwise for nonnegative sums).
#pragma unroll
  for (int off = 32; off > 0; off >>= 1) lsum += __shfl_down(lsum, off);
  if ((tid & 63) == 0) lred[tid >> 6] = lsum;
  __syncthreads();
  if (tid == 0) {
    float t = (lred[0] + lred[1]) + (lred[2] + lred[3]);
    atomicAdd(loss, t * (1.25f / 8388608.f));
  }
}

extern "C" void kernel_launch(void* const* d_in, const int* in_sizes, int n_in,
                              void* d_out, int out_size, void* d_ws, size_t ws_size,
                              hipStream_t stream) {
  const float* x  = (const float*)d_in[0];   // (32,64,64,64) fp32
  const float* cb = (const float*)d_in[1];   // (512,64) fp32
  float* st   = (float*)d_out;               // (32,64,64,64)
  float* idxo = (float*)d_out + ST_ELEMS;    // (32,64,64) as float
  float* loss = (float*)d_out + LOSS_OFF;    // scalar
  uint*  ws   = (uint*)d_ws;                 // 2KB sc + 64KB half2 codebook

  hipMemsetAsync(loss, 0, sizeof(float), stream);  // d_out is poisoned each call
  vq_pre<<<dim3(2), dim3(256), 0, stream>>>(cb, ws);
  vq_kernel<<<dim3(512), dim3(256), 0, stream>>>(x, cb, ws, st, idxo, loss);
}

// Round 7
// 223.570 us; speedup vs baseline: 2.6474x; 1.3432x over previous
//
#include <hip/hip_runtime.h>

// Problem constants (B,C,H,W)=(32,64,64,64), code_size=512
#define HWDIM 4096
#define CDIM  64
#define KDIM  512
#define ST_ELEMS   8388608   // 32*64*64*64
#define LOSS_OFF   8519680   // ST_ELEMS + 32*64*64

// R12: fp16-dot2 prune + sound exact rescan (algorithm validated R9-R11),
// restructured to kill R11's two losses (x-reloads -> 114MB FETCH; fp16-x
// VGPR arrays -> ~116MB scratch WRITE):
//  - fp32 x for BOTH pixels stays PINNED in 128 registers the whole kernel
//    (R8's proven no-spill pattern); rescan + epilogue read pinned regs,
//    zero x-reloads.
//  - fp16 x copies live in swizzled LDS (256 slots x 128B = 32KB; j4 ^=
//    slot&7 XOR-swizzle: slot stride 128B = 32 banks, unswizzled all 64
//    lanes would alias 4 banks = 16-way conflict; swizzled = 2-way = free).
//  - PASS: codebook streamed via s_load_dwordx16 (fp16, 67MB total = half
//    of R8), x-operands via ds_read_b128 per group (hidden under scalar).
//  - MARGIN=6e-4 >= 2A soundly covers fp16 error (A_d <= 2^-11*2*sqrt(S*sc)
//    ~ 7e-5/row-pass + e-formula rounding): true argmin always collected;
//    exact rescan recomputes R8's bit-identical fmaf chain + e-formula;
//    packed-u64 min reproduces first-min tie-break exactly.

#define MARGIN 6e-4f

#define REP64(M) M(0) M(1) M(2) M(3) M(4) M(5) M(6) M(7) M(8) M(9) \
  M(10) M(11) M(12) M(13) M(14) M(15) M(16) M(17) M(18) M(19) \
  M(20) M(21) M(22) M(23) M(24) M(25) M(26) M(27) M(28) M(29) \
  M(30) M(31) M(32) M(33) M(34) M(35) M(36) M(37) M(38) M(39) \
  M(40) M(41) M(42) M(43) M(44) M(45) M(46) M(47) M(48) M(49) \
  M(50) M(51) M(52) M(53) M(54) M(55) M(56) M(57) M(58) M(59) \
  M(60) M(61) M(62) M(63)

typedef unsigned int uint;
typedef _Float16 half2_t __attribute__((ext_vector_type(2)));
typedef uint uv16 __attribute__((ext_vector_type(16)));
typedef __attribute__((address_space(4))) const uv16 cuv16;

// numpy fp32 pairwise sum-of-squares of 64 contiguous values — bit-validated.
__device__ __forceinline__ float np_sumsq64(const float a[64]) {
#pragma clang fp contract(off)
  float v[16];
#pragma unroll
  for (int i = 0; i < 16; ++i) {
    float s0 = a[i]      * a[i];
    float s1 = a[i + 16] * a[i + 16];
    float s2 = a[i + 32] * a[i + 32];
    float s3 = a[i + 48] * a[i + 48];
    v[i] = (s0 + s1) + (s2 + s3);
  }
  float t0 = (v[0] + v[8])  + (v[4] + v[12]);
  float t1 = (v[1] + v[9])  + (v[5] + v[13]);
  float t2 = (v[2] + v[10]) + (v[6] + v[14]);
  float t3 = (v[3] + v[11]) + (v[7] + v[15]);
  return (t0 + t2) + (t1 + t3);
}

// Pack two floats as half2-in-u32 (RNE via _Float16 cast; low half = first).
__device__ __forceinline__ uint pkh(float lo, float hi) {
  unsigned short l = __builtin_bit_cast(unsigned short, (_Float16)lo);
  unsigned short h = __builtin_bit_cast(unsigned short, (_Float16)hi);
  return ((uint)h << 16) | (uint)l;
}

#if __has_builtin(__builtin_amdgcn_fdot2)
#define DOT(acc, xu, cu) acc = __builtin_amdgcn_fdot2( \
    __builtin_bit_cast(half2_t, (uint)(xu)), \
    __builtin_bit_cast(half2_t, (uint)(cu)), acc, false);
#else
#define DOT(acc, xu, cu) { half2_t xa_ = __builtin_bit_cast(half2_t, (uint)(xu)); \
    half2_t cb_ = __builtin_bit_cast(half2_t, (uint)(cu)); \
    acc = __builtin_fmaf((float)xa_.y, (float)cb_.y, \
          __builtin_fmaf((float)xa_.x, (float)cb_.x, acc)); }
#endif

// ---------------- pre-kernel: sc[512] + half2 codebook*256 into ws ---------
__global__ void vq_pre(const float* __restrict__ cb, uint* __restrict__ ws) {
  int k = blockIdx.x * 256 + threadIdx.x;
  if (k < KDIM) {
    float row[64];
#pragma unroll
    for (int c = 0; c < 64; ++c) row[c] = cb[(k << 6) + c];
    ((float*)ws)[k] = np_sumsq64(row);
    uint* dst = ws + 512 + k * 32;
#pragma unroll
    for (int j = 0; j < 32; ++j)
      dst[j] = pkh(row[2 * j] * 256.f, row[2 * j + 1] * 256.f);
  }
}

// ---------------- main kernel ----------------------------------------------
__global__ __launch_bounds__(256)
__attribute__((amdgpu_waves_per_eu(2, 2)))
void vq_kernel(
    const float* __restrict__ x, const float* __restrict__ cb,
    const uint* __restrict__ ws,
    float* __restrict__ st, float* __restrict__ idxo, float* __restrict__ loss)
{
  __shared__ __align__(16) uint xh_l[256 * 32];   // 32 KB swizzled fp16 x
  __shared__ float scL[KDIM];
  __shared__ unsigned long long mrg[256];
  __shared__ float lred[4];

  const int tid = threadIdx.x;
  const int pix = tid & 127;                       // pixel-pair slot
  // tid>>7 IS wave-uniform (64-thread waves don't straddle 128) — force SGPR.
  const int khalf = __builtin_amdgcn_readfirstlane(tid >> 7);
  const int b   = blockIdx.x & 31;
  const int p   = ((blockIdx.x >> 5) << 8) + pix;  // px A; px B = p+128

  // sc -> LDS (exact values from pre-kernel; bit-identical np_sumsq64).
  scL[tid]       = ((const float*)ws)[tid];
  scL[tid + 256] = ((const float*)ws)[tid + 256];

  // Constant-AS view of the packed fp16 codebook (64B chunks): wave-uniform
  // addresses -> s_load_dwordx16 scalar streaming (row = 2 chunks = 128B).
  cuv16* cw = (cuv16*)(uintptr_t)(ws + 512);

  const float* xpA = x + (size_t)b * (CDIM * HWDIM) + p;
  const float* xpB = xpA + 128;

  // Load BOTH pixels' points into 128 named, pinned registers (R8 pattern).
#define XLOAD(i) float x##i = xpA[(i) * HWDIM]; asm("" : "+v"(x##i));
#define YLOAD(i) float y##i = xpB[(i) * HWDIM]; asm("" : "+v"(y##i));
  REP64(XLOAD)
  REP64(YLOAD)
#undef XLOAD
#undef YLOAD

  // Exact S per pixel — R8's bit-identical numpy pairwise tree.
#define SQT(V, i, j, k2, l) \
    float v##i = ((V##i * V##i) + (V##j * V##j)) + ((V##k2 * V##k2) + (V##l * V##l));
#define SUMSQ_TREE(V, OUT) { \
    _Pragma("clang fp contract(off)") \
    SQT(V,0,16,32,48) SQT(V,1,17,33,49) SQT(V,2,18,34,50) SQT(V,3,19,35,51) \
    SQT(V,4,20,36,52) SQT(V,5,21,37,53) SQT(V,6,22,38,54) SQT(V,7,23,39,55) \
    SQT(V,8,24,40,56) SQT(V,9,25,41,57) SQT(V,10,26,42,58) SQT(V,11,27,43,59) \
    SQT(V,12,28,44,60) SQT(V,13,29,45,61) SQT(V,14,30,46,62) SQT(V,15,31,47,63) \
    float t0 = (v0 + v8)  + (v4 + v12); \
    float t1 = (v1 + v9)  + (v5 + v13); \
    float t2 = (v2 + v10) + (v6 + v14); \
    float t3 = (v3 + v11) + (v7 + v15); \
    OUT = (t0 + t2) + (t1 + t3); }

  float S_A, S_B;
  SUMSQ_TREE(x, S_A)
  SUMSQ_TREE(y, S_B)
#undef SUMSQ_TREE
#undef SQT

  // fp16 x copies -> swizzled LDS. Only khalf==0 writes (khalf==1 threads
  // hold identical data for the same pixels). Swizzle: 16B-granule index
  // j4 XOR (slot&7) — bijective within the slot's 8 granules.
#define WR8(SLOT, J4, E0,E1,E2,E3,E4,E5,E6,E7) { \
    uint4 w_; w_.x = pkh(E0,E1); w_.y = pkh(E2,E3); \
    w_.z = pkh(E4,E5); w_.w = pkh(E6,E7); \
    *reinterpret_cast<uint4*>( \
        &xh_l[((SLOT) << 5) + (((J4) ^ ((SLOT) & 7)) << 2)]) = w_; }
  if (!khalf) {
    WR8(pix, 0, x0,x1,x2,x3,x4,x5,x6,x7)
    WR8(pix, 1, x8,x9,x10,x11,x12,x13,x14,x15)
    WR8(pix, 2, x16,x17,x18,x19,x20,x21,x22,x23)
    WR8(pix, 3, x24,x25,x26,x27,x28,x29,x30,x31)
    WR8(pix, 4, x32,x33,x34,x35,x36,x37,x38,x39)
    WR8(pix, 5, x40,x41,x42,x43,x44,x45,x46,x47)
    WR8(pix, 6, x48,x49,x50,x51,x52,x53,x54,x55)
    WR8(pix, 7, x56,x57,x58,x59,x60,x61,x62,x63)
    WR8(pix + 128, 0, y0,y1,y2,y3,y4,y5,y6,y7)
    WR8(pix + 128, 1, y8,y9,y10,y11,y12,y13,y14,y15)
    WR8(pix + 128, 2, y16,y17,y18,y19,y20,y21,y22,y23)
    WR8(pix + 128, 3, y24,y25,y26,y27,y28,y29,y30,y31)
    WR8(pix + 128, 4, y32,y33,y34,y35,y36,y37,y38,y39)
    WR8(pix + 128, 5, y40,y41,y42,y43,y44,y45,y46,y47)
    WR8(pix + 128, 6, y48,y49,y50,y51,y52,y53,y54,y55)
    WR8(pix + 128, 7, y56,y57,y58,y59,y60,y61,y62,y63)
  }
#undef WR8
  __syncthreads();

  // ---- PASS: fp16 dot2 over this half's 256 rows; candidate bitmasks
  // (f < runmin + MARGIN). c scaled by 256 -> f = sc - 2*d/256 -> -0.0078125.
  const int qbase = khalf << 8;
  float runA = __builtin_inff(), runB = __builtin_inff();
  uint mA0 = 0, mA1 = 0, mA2 = 0, mA3 = 0, mA4 = 0, mA5 = 0, mA6 = 0, mA7 = 0;
  uint mB0 = 0, mB1 = 0, mB2 = 0, mB3 = 0, mB4 = 0, mB5 = 0, mB6 = 0, mB7 = 0;

#define RD16(SLOT, J4B, U) { \
    const int sb_ = ((SLOT) << 5); const int sw_ = ((SLOT) & 7); \
    uint4 r0_ = *reinterpret_cast<const uint4*>(&xh_l[sb_ + ((((J4B) + 0) ^ sw_) << 2)]); \
    uint4 r1_ = *reinterpret_cast<const uint4*>(&xh_l[sb_ + ((((J4B) + 1) ^ sw_) << 2)]); \
    uint4 r2_ = *reinterpret_cast<const uint4*>(&xh_l[sb_ + ((((J4B) + 2) ^ sw_) << 2)]); \
    uint4 r3_ = *reinterpret_cast<const uint4*>(&xh_l[sb_ + ((((J4B) + 3) ^ sw_) << 2)]); \
    U[0]=r0_.x; U[1]=r0_.y; U[2]=r0_.z; U[3]=r0_.w; \
    U[4]=r1_.x; U[5]=r1_.y; U[6]=r1_.z; U[7]=r1_.w; \
    U[8]=r2_.x; U[9]=r2_.y; U[10]=r2_.z; U[11]=r2_.w; \
    U[12]=r3_.x; U[13]=r3_.y; U[14]=r3_.z; U[15]=r3_.w; }

  // Two scopes of 4 live uv16 (64 SGPR peak — R8's proven chunk schedule).
#define PASSJ(J, MA, MB) \
  for (int g = 0; g < 8; ++g) { \
    const int krow = qbase + ((J) << 5) + (g << 2); \
    const int rb = krow << 1;   /* row k = chunks 2k, 2k+1 */ \
    float d0a = 0.f, d1a = 0.f, d2a = 0.f, d3a = 0.f; \
    float d0b = 0.f, d1b = 0.f, d2b = 0.f, d3b = 0.f; \
    {  /* channels 0..31 */ \
      uint uA[16], uB[16]; \
      RD16(pix, 0, uA) RD16(pix + 128, 0, uB) \
      uv16 q0 = cw[rb], q1 = cw[rb + 2], q2 = cw[rb + 4], q3 = cw[rb + 6]; \
      _Pragma("unroll") \
      for (int t = 0; t < 16; ++t) { \
        DOT(d0a, uA[t], q0[t]) DOT(d0b, uB[t], q0[t]) \
        DOT(d1a, uA[t], q1[t]) DOT(d1b, uB[t], q1[t]) \
        DOT(d2a, uA[t], q2[t]) DOT(d2b, uB[t], q2[t]) \
        DOT(d3a, uA[t], q3[t]) DOT(d3b, uB[t], q3[t]) \
      } \
    } \
    {  /* channels 32..63 */ \
      uint uA[16], uB[16]; \
      RD16(pix, 4, uA) RD16(pix + 128, 4, uB) \
      uv16 q0 = cw[rb + 1], q1 = cw[rb + 3], q2 = cw[rb + 5], q3 = cw[rb + 7]; \
      _Pragma("unroll") \
      for (int t = 0; t < 16; ++t) { \
        DOT(d0a, uA[t], q0[t]) DOT(d0b, uB[t], q0[t]) \
        DOT(d1a, uA[t], q1[t]) DOT(d1b, uB[t], q1[t]) \
        DOT(d2a, uA[t], q2[t]) DOT(d2b, uB[t], q2[t]) \
        DOT(d3a, uA[t], q3[t]) DOT(d3b, uB[t], q3[t]) \
      } \
    } \
    const float s0 = scL[krow], s1 = scL[krow + 1]; \
    const float s2 = scL[krow + 2], s3 = scL[krow + 3]; \
    float f0a = __builtin_fmaf(-0.0078125f, d0a, s0); \
    float f1a = __builtin_fmaf(-0.0078125f, d1a, s1); \
    float f2a = __builtin_fmaf(-0.0078125f, d2a, s2); \
    float f3a = __builtin_fmaf(-0.0078125f, d3a, s3); \
    float f0b = __builtin_fmaf(-0.0078125f, d0b, s0); \
    float f1b = __builtin_fmaf(-0.0078125f, d1b, s1); \
    float f2b = __builtin_fmaf(-0.0078125f, d2b, s2); \
    float f3b = __builtin_fmaf(-0.0078125f, d3b, s3); \
    const float thA = runA + MARGIN, thB = runB + MARGIN; \
    const uint bit0 = 1u << (g << 2); \
    MA |= (f0a < thA ? bit0 : 0u) | (f1a < thA ? (bit0 << 1) : 0u) \
        | (f2a < thA ? (bit0 << 2) : 0u) | (f3a < thA ? (bit0 << 3) : 0u); \
    MB |= (f0b < thB ? bit0 : 0u) | (f1b < thB ? (bit0 << 1) : 0u) \
        | (f2b < thB ? (bit0 << 2) : 0u) | (f3b < thB ? (bit0 << 3) : 0u); \
    runA = fminf(runA, fminf(fminf(f0a, f1a), fminf(f2a, f3a))); \
    runB = fminf(runB, fminf(fminf(f0b, f1b), fminf(f2b, f3b))); \
  }
  PASSJ(0, mA0, mB0)
  PASSJ(1, mA1, mB1)
  PASSJ(2, mA2, mB2)
  PASSJ(3, mA3, mB3)
  PASSJ(4, mA4, mB4)
  PASSJ(5, mA5, mB5)
  PASSJ(6, mA6, mB6)
  PASSJ(7, mA7, mB7)
#undef PASSJ
#undef RD16

  // ---- Exact rescan of candidates using the PINNED fp32 regs (no reloads).
  // Bit-identical R8 fmaf chain (ascending c) + e-formula.
#define FQ(d, R, V, A0, A1, A2, A3) \
    d = __builtin_fmaf(V##A0, R.x, d); d = __builtin_fmaf(V##A1, R.y, d); \
    d = __builtin_fmaf(V##A2, R.z, d); d = __builtin_fmaf(V##A3, R.w, d);
#define RESROW(d, rw, V) \
    { float4 r0 = rw[0], r1 = rw[1], r2 = rw[2], r3 = rw[3]; \
      FQ(d, r0, V, 0, 1, 2, 3)      FQ(d, r1, V, 4, 5, 6, 7) \
      FQ(d, r2, V, 8, 9, 10, 11)    FQ(d, r3, V, 12, 13, 14, 15) \
      r0 = rw[4]; r1 = rw[5]; r2 = rw[6]; r3 = rw[7]; \
      FQ(d, r0, V, 16, 17, 18, 19)  FQ(d, r1, V, 20, 21, 22, 23) \
      FQ(d, r2, V, 24, 25, 26, 27)  FQ(d, r3, V, 28, 29, 30, 31) \
      r0 = rw[8]; r1 = rw[9]; r2 = rw[10]; r3 = rw[11]; \
      FQ(d, r0, V, 32, 33, 34, 35)  FQ(d, r1, V, 36, 37, 38, 39) \
      FQ(d, r2, V, 40, 41, 42, 43)  FQ(d, r3, V, 44, 45, 46, 47) \
      r0 = rw[12]; r1 = rw[13]; r2 = rw[14]; r3 = rw[15]; \
      FQ(d, r0, V, 48, 49, 50, 51)  FQ(d, r1, V, 52, 53, 54, 55) \
      FQ(d, r2, V, 56, 57, 58, 59)  FQ(d, r3, V, 60, 61, 62, 63) }

#define RES1(MM, J, SS, PK, V) \
    { uint m_ = MM; \
      while (__any(m_ != 0u)) { \
        if (m_ != 0u) { \
          const int kk = qbase + ((J) << 5) + (__ffs(m_) - 1); \
          const float4* rw = (const float4*)(cb + ((size_t)kk << 6)); \
          float d = 0.f; \
          RESROW(d, rw, V) \
          float e; \
          { _Pragma("clang fp contract(off)") e = (SS - (d + d)) + scL[kk]; } \
          unsigned long long c_ = \
              ((unsigned long long)__float_as_uint(e) << 32) | (uint)kk; \
          if (c_ < PK) PK = c_; \
          m_ &= m_ - 1u; \
        } \
      } }

  unsigned long long pkA = ~0ull, pkB = ~0ull;
  RES1(mA0, 0, S_A, pkA, x) RES1(mA1, 1, S_A, pkA, x)
  RES1(mA2, 2, S_A, pkA, x) RES1(mA3, 3, S_A, pkA, x)
  RES1(mA4, 4, S_A, pkA, x) RES1(mA5, 5, S_A, pkA, x)
  RES1(mA6, 6, S_A, pkA, x) RES1(mA7, 7, S_A, pkA, x)
  RES1(mB0, 0, S_B, pkB, y) RES1(mB1, 1, S_B, pkB, y)
  RES1(mB2, 2, S_B, pkB, y) RES1(mB3, 3, S_B, pkB, y)
  RES1(mB4, 4, S_B, pkB, y) RES1(mB5, 5, S_B, pkB, y)
  RES1(mB6, 6, S_B, pkB, y) RES1(mB7, 7, S_B, pkB, y)
#undef RES1
#undef RESROW
#undef FQ

  // ---- Cross-half exact merge (u64 min == first-min semantics: distances
  // positive -> fp32 bits order identically; idx in low word).
  if (khalf) { mrg[pix] = pkA; mrg[pix + 128] = pkB; }
  __syncthreads();

  float lsum = 0.f;
  if (!khalf) {
    { unsigned long long o = mrg[pix];       if (o < pkA) pkA = o; }
    { unsigned long long o = mrg[pix + 128]; if (o < pkB) pkB = o; }
    const int bestiA = (int)(pkA & 0xffffffffull);
    const int bestiB = (int)(pkB & 0xffffffffull);

    // Epilogue from PINNED regs — identical to R8 (no reloads).
    const float* crowA = cb + (bestiA << 6);
    const float* crowB = cb + (bestiB << 6);
    float* stpA = st + (size_t)b * (CDIM * HWDIM) + p;
    float* stpB = stpA + 128;
    float lsumA = 0.f, lsumB = 0.f;
#define EPIA(i) { float cv = crowA[i]; float df; \
    { _Pragma("clang fp contract(off)") df = cv - x##i; } \
    lsumA = __builtin_fmaf(df, df, lsumA); stpA[(i) * HWDIM] = cv; }
#define EPIB(i) { float cv = crowB[i]; float df; \
    { _Pragma("clang fp contract(off)") df = cv - y##i; } \
    lsumB = __builtin_fmaf(df, df, lsumB); stpB[(i) * HWDIM] = cv; }
    REP64(EPIA)
    REP64(EPIB)
#undef EPIA
#undef EPIB

    idxo[b * HWDIM + p]       = (float)bestiA;
    idxo[b * HWDIM + p + 128] = (float)bestiB;
    lsum = lsumA + lsumB;
  }

  // Block reduce loss, one atomic per block (R8's exact tree; waves 2-3
  // contribute exact zeros, t + 0.0f == t bitwise for nonnegative sums).
#pragma unroll
  for (int off = 32; off > 0; off >>= 1) lsum += __shfl_down(lsum, off);
  if ((tid & 63) == 0) lred[tid >> 6] = lsum;
  __syncthreads();
  if (tid == 0) {
    float t = (lred[0] + lred[1]) + (lred[2] + lred[3]);
    atomicAdd(loss, t * (1.25f / 8388608.f));
  }
}

extern "C" void kernel_launch(void* const* d_in, const int* in_sizes, int n_in,
                              void* d_out, int out_size, void* d_ws, size_t ws_size,
                              hipStream_t stream) {
  const float* x  = (const float*)d_in[0];   // (32,64,64,64) fp32
  const float* cb = (const float*)d_in[1];   // (512,64) fp32
  float* st   = (float*)d_out;               // (32,64,64,64)
  float* idxo = (float*)d_out + ST_ELEMS;    // (32,64,64) as float
  float* loss = (float*)d_out + LOSS_OFF;    // scalar
  uint*  ws   = (uint*)d_ws;                 // 2KB sc + 64KB half2 codebook

  hipMemsetAsync(loss, 0, sizeof(float), stream);  // d_out is poisoned each call
  vq_pre<<<dim3(2), dim3(256), 0, stream>>>(cb, ws);
  vq_kernel<<<dim3(512), dim3(256), 0, stream>>>(x, cb, ws, st, idxo, loss);
}